// Round 5
// baseline (93.293 us; speedup 1.0000x reference)
//
#include <hip/hip_runtime.h>

// ContinuousCRF: mean-field CRF on a 96x96 grid, 3 classes, 5 iterations.
// The dense [N,N] pairwise kernel is a translation-invariant 11x11
// circular-mask convolution (radius 5, weight exp(-dist), no center tap).
// Each iteration: q = softmax(unary + Comp @ conv(q)).
//
// Round 5: R3's 2-dispatch halo fusion, but compiled RIGHT. R3's inner loop
// had runtime bounds + per-tap buffer ternary -> no unroll -> each tap paid
// ~120cyc LDS latency serially (~22us). Here the k-loop is #pragma-unrolled
// over template-constant K, so R/o are compile-time, the buffer select is a
// hoisted array pointer, and the 81-tap loop fully unrolls into batched
// ds_read_b128 like R4. 2 dispatches (K=3 + K=2) replace 5 -> saves ~4.5us
// of serialized dispatch latency for ~2us of redundant halo compute.

constexpr int HH = 96, WW = 96, NN = HH * WW;
constexpr int T = 8;

template <int K, bool FIRST, bool LAST>
__global__ __launch_bounds__(256) void crf_multi(
    const float* __restrict__ unary,   // [3][9216] planes
    const float* __restrict__ comp,    // [3][3]
    const float4* __restrict__ qin,    // q in (if !FIRST)
    float4* __restrict__ qnext,        // q out (if !LAST)
    float* __restrict__ qout)          // [3][9216] final q planes (if LAST)
{
    constexpr int EXT = T + 10 * K;    // K=3: 38, K=2: 28
    constexpr int LD = EXT + 1;        // +1 float4 pad vs bank conflicts
    __shared__ float4 qa[EXT][LD];
    __shared__ float4 qb[EXT][LD];
    __shared__ float wtab[121];

    const int tid = threadIdx.x;

    // 11x11 conv weight table (exact math, once per block).
    if (tid < 121) {
        int dy = tid / 11 - 5, dx = tid % 11 - 5;
        int d2 = dy * dy + dx * dx;
        wtab[tid] = (d2 > 0 && d2 <= 25) ? expf(-sqrtf((float)d2)) : 0.0f;
    }

    // Compatibility matrix (3x3 row-major), wave-uniform scalar loads.
    const float c00 = comp[0], c01 = comp[1], c02 = comp[2];
    const float c10 = comp[3], c11 = comp[4], c12 = comp[5];
    const float c20 = comp[6], c21 = comp[7], c22 = comp[8];

    // Global coords of ext-region origin (may be off-image).
    const int bx0 = blockIdx.x * T - 5 * K;
    const int by0 = blockIdx.y * T - 5 * K;

    // Stage q over EXT x EXT. FIRST: q0 = softmax(unary); else float4 copy.
    // Off-image -> q = 0 (zero connectivity outside the grid).
    for (int i = tid; i < EXT * EXT; i += 256) {
        int hy = i / EXT, hx = i - hy * EXT;
        int gy = by0 + hy, gx = bx0 + hx;
        float4 q = make_float4(0.f, 0.f, 0.f, 0.f);
        if (gy >= 0 && gy < HH && gx >= 0 && gx < WW) {
            int n = gy * WW + gx;
            if (FIRST) {
                float z0 = unary[n], z1 = unary[NN + n], z2 = unary[2 * NN + n];
                float mx = fmaxf(z0, fmaxf(z1, z2));
                float e0 = expf(z0 - mx), e1 = expf(z1 - mx), e2 = expf(z2 - mx);
                float inv = 1.0f / (e0 + e1 + e2);
                q = make_float4(e0 * inv, e1 * inv, e2 * inv, 0.f);
            } else {
                q = qin[n];
            }
        }
        qa[hy][hx] = q;
    }
    __syncthreads();   // also covers wtab

    constexpr int XLO[11] = {5, 2, 1, 1, 1, 0, 1, 1, 1, 2, 5};
    constexpr int XHI[11] = {5, 8, 9, 9, 9, 10, 9, 9, 9, 8, 5};

#pragma unroll
    for (int k = 1; k <= K; ++k) {
        const int R = T + 10 * (K - k);   // compile-time after unroll
        const int o = 5 * k;
        float4 (*src)[LD] = (k & 1) ? qa : qb;   // hoisted: one select per k
        float4 (*dst)[LD] = (k & 1) ? qb : qa;

        for (int i = tid; i < R * R; i += 256) {
            int py = i / R, px = i - py * R;
            int ey = o + py, ex = o + px;
            int gy = by0 + ey, gx = bx0 + ex;
            float4 qv = make_float4(0.f, 0.f, 0.f, 0.f);
            if (gy >= 0 && gy < HH && gx >= 0 && gx < WW) {
                float m0 = 0.f, m1 = 0.f, m2 = 0.f;
#pragma unroll
                for (int dyi = 0; dyi < 11; ++dyi) {
#pragma unroll
                    for (int dxi = XLO[dyi]; dxi <= XHI[dyi]; ++dxi) {
                        float w = wtab[dyi * 11 + dxi];  // uniform broadcast
                        float4 q = src[ey - 5 + dyi][ex - 5 + dxi];
                        m0 = fmaf(w, q.x, m0);
                        m1 = fmaf(w, q.y, m1);
                        m2 = fmaf(w, q.z, m2);
                    }
                }
                float t0 = c00 * m0 + c01 * m1 + c02 * m2;
                float t1 = c10 * m0 + c11 * m1 + c12 * m2;
                float t2 = c20 * m0 + c21 * m1 + c22 * m2;

                int n = gy * WW + gx;
                float z0 = unary[n] + t0;
                float z1 = unary[NN + n] + t1;
                float z2 = unary[2 * NN + n] + t2;

                float mx = fmaxf(z0, fmaxf(z1, z2));
                float e0 = expf(z0 - mx), e1 = expf(z1 - mx), e2 = expf(z2 - mx);
                float inv = 1.0f / (e0 + e1 + e2);
                qv = make_float4(e0 * inv, e1 * inv, e2 * inv, 0.f);

                if (k == K) {
                    // Region == the block's own 8x8 tile (all in-image).
                    if (LAST) {
                        qout[n] = qv.x;
                        qout[NN + n] = qv.y;
                        qout[2 * NN + n] = qv.z;
                    } else {
                        qnext[n] = qv;
                    }
                }
            }
            if (k < K) dst[ey][ex] = qv;
        }
        if (k < K) __syncthreads();
        // Next iter reads only ext coords [o, o+R) — exactly what was written.
    }
}

extern "C" void kernel_launch(void* const* d_in, const int* in_sizes, int n_in,
                              void* d_out, int out_size, void* d_ws, size_t ws_size,
                              hipStream_t stream) {
    const float* unary = (const float*)d_in[0];
    const float* comp = (const float*)d_in[1];
    float* out = (float*)d_out;

    float4* qMid = (float4*)d_ws;   // 9216 * 16 B = 144 KiB

    dim3 grid(WW / T, HH / T);      // 12x12 = 144 blocks
    dim3 block(256);

    // Iters 1-3 (halo 15), then iters 4-5 (halo 10).
    crf_multi<3, true,  false><<<grid, block, 0, stream>>>(unary, comp, nullptr, qMid, nullptr);
    crf_multi<2, false, true ><<<grid, block, 0, stream>>>(unary, comp, qMid, nullptr, out);
}

// Round 6
// 79.565 us; speedup vs baseline: 1.1725x; 1.1725x over previous
//
#include <hip/hip_runtime.h>

// ContinuousCRF: mean-field CRF on a 96x96 grid, 3 classes, 5 iterations.
// The dense [N,N] pairwise kernel is a translation-invariant 11x11
// circular-mask convolution (radius 5, weight exp(-dist), no center tap).
// Each iteration: q = softmax(unary + Comp @ conv(q)).
//
// Round 6: restore the measured-best structure (R4, 79.8us). Mapped space:
//   1 coop dispatch (grid.sync):           135us  (12us/barrier)
//   2 fused dispatches (halo redundancy):  92-93us (x2, both attempts)
//   5 plain dispatches, 36 blk x 256 thr:  81us
//   5 plain dispatches, 144 blk x 64 thr:  79.8us  <-- this file
// Fixed harness cost ~70us (268MB ws-poison fill at 85% HBM peak + restore);
// controllable part ~9.3us = 5 serialized graph nodes at the ~2us dispatch
// latency floor; kernel work itself ~0.5us each (VALUBusy <5%).

constexpr int HH = 96, WW = 96, NN = HH * WW;
constexpr int T = 8, HALO = 5, EXT = T + 2 * HALO; // 18

template <bool FIRST, bool LAST>
__global__ __launch_bounds__(64) void crf_iter(
    const float* __restrict__ unary,   // [3][9216] planes
    const float* __restrict__ comp,    // [3][3]
    const float4* __restrict__ qin,    // q from previous iter (if !FIRST)
    float4* __restrict__ qnext,        // q out as float4 (if !LAST)
    float* __restrict__ qout)          // [3][9216] final q planes (if LAST)
{
    __shared__ float4 qs[EXT][EXT + 1];  // q over tile+halo (+1 float4 pad)
    __shared__ float wtab[121];          // 11x11 conv weights

    const int tid = threadIdx.x;

    // Conv weight table (exact math; 2 passes of 64 threads).
    for (int i = tid; i < 121; i += 64) {
        int dy = i / 11 - 5, dx = i % 11 - 5;
        int d2 = dy * dy + dx * dx;
        wtab[i] = (d2 > 0 && d2 <= 25) ? expf(-sqrtf((float)d2)) : 0.0f;
    }

    // Compatibility matrix (3x3 row-major), wave-uniform scalar loads.
    const float c00 = comp[0], c01 = comp[1], c02 = comp[2];
    const float c10 = comp[3], c11 = comp[4], c12 = comp[5];
    const float c20 = comp[6], c21 = comp[7], c22 = comp[8];

    const int bx0 = blockIdx.x * T - HALO;
    const int by0 = blockIdx.y * T - HALO;

    // Stage q over the 18x18 halo region. FIRST: q0 = softmax(unary);
    // otherwise a straight float4 copy. Off-image -> q = 0.
    for (int i = tid; i < EXT * EXT; i += 64) {
        int hy = i / EXT, hx = i - hy * EXT;
        int gy = by0 + hy, gx = bx0 + hx;
        float4 q = make_float4(0.f, 0.f, 0.f, 0.f);
        if (gy >= 0 && gy < HH && gx >= 0 && gx < WW) {
            int n = gy * WW + gx;
            if (FIRST) {
                float z0 = unary[n], z1 = unary[NN + n], z2 = unary[2 * NN + n];
                float mx = fmaxf(z0, fmaxf(z1, z2));
                float e0 = expf(z0 - mx), e1 = expf(z1 - mx), e2 = expf(z2 - mx);
                float inv = 1.0f / (e0 + e1 + e2);
                q = make_float4(e0 * inv, e1 * inv, e2 * inv, 0.f);
            } else {
                q = qin[n];
            }
        }
        qs[hy][hx] = q;
    }
    __syncthreads();   // single-wave block: near-free barrier

    // 11x11 conv, static per-row dx bounds (circle mask) -> 81 taps.
    const int ty = tid >> 3, tx = tid & 7;   // 8x8 tile, 1 px/thread
    float m0 = 0.f, m1 = 0.f, m2 = 0.f;
    constexpr int XLO[11] = {5, 2, 1, 1, 1, 0, 1, 1, 1, 2, 5};
    constexpr int XHI[11] = {5, 8, 9, 9, 9, 10, 9, 9, 9, 8, 5};
#pragma unroll
    for (int dyi = 0; dyi < 11; ++dyi) {
#pragma unroll
        for (int dxi = XLO[dyi]; dxi <= XHI[dyi]; ++dxi) {
            float w = wtab[dyi * 11 + dxi];   // wave-uniform broadcast
            float4 q = qs[ty + dyi][tx + dxi];
            m0 = fmaf(w, q.x, m0);
            m1 = fmaf(w, q.y, m1);
            m2 = fmaf(w, q.z, m2);
        }
    }

    float t0 = c00 * m0 + c01 * m1 + c02 * m2;
    float t1 = c10 * m0 + c11 * m1 + c12 * m2;
    float t2 = c20 * m0 + c21 * m1 + c22 * m2;

    const int n = (blockIdx.y * T + ty) * WW + (blockIdx.x * T + tx);
    float z0 = unary[n] + t0;
    float z1 = unary[NN + n] + t1;
    float z2 = unary[2 * NN + n] + t2;

    float mx = fmaxf(z0, fmaxf(z1, z2));
    float e0 = expf(z0 - mx), e1 = expf(z1 - mx), e2 = expf(z2 - mx);
    float inv = 1.0f / (e0 + e1 + e2);

    if (LAST) {
        qout[n] = e0 * inv;
        qout[NN + n] = e1 * inv;
        qout[2 * NN + n] = e2 * inv;
    } else {
        qnext[n] = make_float4(e0 * inv, e1 * inv, e2 * inv, 0.f);
    }
}

extern "C" void kernel_launch(void* const* d_in, const int* in_sizes, int n_in,
                              void* d_out, int out_size, void* d_ws, size_t ws_size,
                              hipStream_t stream) {
    const float* unary = (const float*)d_in[0];
    const float* comp = (const float*)d_in[1];
    float* out = (float*)d_out;

    // Ping-pong q buffers in workspace: 2 * 9216 * 16 B = 288 KiB.
    float4* qA = (float4*)d_ws;
    float4* qB = qA + NN;

    dim3 grid(WW / T, HH / T);    // 12x12 = 144 blocks (1 wave each)
    dim3 block(64);

    crf_iter<true,  false><<<grid, block, 0, stream>>>(unary, comp, nullptr, qA, nullptr);
    crf_iter<false, false><<<grid, block, 0, stream>>>(unary, comp, qA, qB, nullptr);
    crf_iter<false, false><<<grid, block, 0, stream>>>(unary, comp, qB, qA, nullptr);
    crf_iter<false, false><<<grid, block, 0, stream>>>(unary, comp, qA, qB, nullptr);
    crf_iter<false, true ><<<grid, block, 0, stream>>>(unary, comp, qB, nullptr, out);
}